// Round 1
// baseline (3832.206 us; speedup 1.0000x reference)
//
#include <hip/hip_runtime.h>

// Spatialize: y[b,c,t] = sum_{j=0}^{K-1} ir[j,c] * x[b, t-j],  t in [12500, 137500)
// Inputs:  d_in[0] = x  (64, 150000) f32
//          d_in[1] = ir (10000, 2)   f32  (interleaved L/R)
// Output:  d_out = y (64, 2, 125000) f32
//
// Key fact: t - j >= 2501 and t_max + 0 <= 138451 < 150000 -> no bounds checks
// on x reads anywhere. Pure compute-bound fp32 FIR (320 GFLOP, ~2.04 ms roofline).

#define K_TAPS   10000
#define T_LEN    150000
#define OUT_T0   12500
#define OUT_T1   137500
#define OUT_LEN  125000
#define BATCH    64

#define TT       1024            // outputs per workgroup
#define PAD      10240           // back-window, multiple of 4, >= K_TAPS-1
#define LDSF     (TT + PAD)      // 11264 floats = 44 KB LDS
#define NTHREADS 256
#define NGROUPS  (K_TAPS / 4)    // 2500 groups of 4 taps

__device__ __forceinline__ void group4(const float4& lo, const float4& hi,
                                       const float* __restrict__ irp,
                                       float accL[4], float accR[4])
{
    // window w[i] = xs[A0 + i]; outputs use w[4 + r - dj], dj,r in [0,4)
    float w[8] = {lo.x, lo.y, lo.z, lo.w, hi.x, hi.y, hi.z, hi.w};
#pragma unroll
    for (int dj = 0; dj < 4; ++dj) {
        const float sL = irp[2 * dj];
        const float sR = irp[2 * dj + 1];
#pragma unroll
        for (int r = 0; r < 4; ++r) {
            accL[r] = fmaf(sL, w[4 + r - dj], accL[r]);
            accR[r] = fmaf(sR, w[4 + r - dj], accR[r]);
        }
    }
}

__global__ __launch_bounds__(NTHREADS) void spatialize_fir(
    const float* __restrict__ x, const float* __restrict__ ir,
    float* __restrict__ out)
{
    __shared__ float xs[LDSF];

    const int tile = blockIdx.x;
    const int b    = blockIdx.y;
    const int t0   = OUT_T0 + tile * TT;     // first output time of this tile
    const int g0   = t0 - PAD;               // xs[q] = x[b, g0 + q]; g0 >= 2260, %4==0
    const int lid  = threadIdx.x;

    // ---- stage x window into LDS (coalesced float4) ----
    {
        const float4* __restrict__ src =
            reinterpret_cast<const float4*>(x + (size_t)b * T_LEN + g0);
        float4* dst = reinterpret_cast<float4*>(xs);
#pragma unroll
        for (int i = 0; i < LDSF / 4 / NTHREADS; ++i)   // 11 iters
            dst[lid + i * NTHREADS] = src[lid + i * NTHREADS];
    }
    __syncthreads();

    float accL[4] = {0.f, 0.f, 0.f, 0.f};
    float accR[4] = {0.f, 0.f, 0.f, 0.f};

    // anchor A0(G) = lid*4 + PAD - 4 - 4G ; window = xs[A0 .. A0+7]
    int p = lid * 4 + (PAD - 4);
    float4 lo = *reinterpret_cast<const float4*>(&xs[p]);
    float4 hi = *reinterpret_cast<const float4*>(&xs[p + 4]);

#pragma unroll 1
    for (int G = 0; G < NGROUPS; G += 2) {
        float4 nlo = *reinterpret_cast<const float4*>(&xs[p - 4]);
        group4(lo, hi, ir + 8 * G, accL, accR);
        float4 nlo2 = *reinterpret_cast<const float4*>(&xs[p - 8]);
        group4(nlo, lo, ir + 8 * (G + 1), accL, accR);
        hi = nlo2;           // window for G+2: lo'' = xs[A0-8], hi'' = xs[A0-4]
        lo = nlo2;           // (placeholder, fixed below)
        // correct rotation:
        lo = nlo2; hi = nlo;
        p -= 8;
    }

    // ---- store: (b, c, t-OUT_T0), both channels ----
    const int T = t0 + lid * 4;
    float* outL = out + (size_t)b * (2 * OUT_LEN) + (T - OUT_T0);
    float* outR = outL + OUT_LEN;
    if (T + 3 < OUT_T1) {
        *reinterpret_cast<float4*>(outL) = make_float4(accL[0], accL[1], accL[2], accL[3]);
        *reinterpret_cast<float4*>(outR) = make_float4(accR[0], accR[1], accR[2], accR[3]);
    } else {
#pragma unroll
        for (int r = 0; r < 4; ++r)
            if (T + r < OUT_T1) { outL[r] = accL[r]; outR[r] = accR[r]; }
    }
}

extern "C" void kernel_launch(void* const* d_in, const int* in_sizes, int n_in,
                              void* d_out, int out_size, void* d_ws, size_t ws_size,
                              hipStream_t stream)
{
    (void)in_sizes; (void)n_in; (void)d_ws; (void)ws_size; (void)out_size;
    const float* x  = (const float*)d_in[0];
    const float* ir = (const float*)d_in[1];
    float* out      = (float*)d_out;

    dim3 grid((OUT_LEN + TT - 1) / TT, BATCH);   // (123, 64)
    dim3 block(NTHREADS);
    hipLaunchKernelGGL(spatialize_fir, grid, block, 0, stream, x, ir, out);
}

// Round 3
// 491.636 us; speedup vs baseline: 7.7948x; 7.7948x over previous
//
#include <hip/hip_runtime.h>

// Spatialize via MFMA: y[b,c,t] = sum_j ir[j,c] * x[b,t-j], t in [12500,137500)
//
// GEMM form, K indexed by absolute x position p:
//   C[m][b] (+)= A[m][kk] * B[kk][b]
//   A[m][kk] = hpad[D_i + m - kk]   (Toeplitz slice of h, per channel)
//   B[kk][b] = x[b][p0_i + kk]
// A lives in a rolling LDS ring: chunk i+1's A == chunk i's A shifted by KC rows,
// so only KC new rows (KC*KC*2ch bf16) are built per chunk.

#define K_TAPS  10000
#define T_LEN   150000
#define OUT_T0  12500
#define OUT_T1  137500
#define OUT_LEN 125000
#define BATCH   64

#define TM    256            // output times per workgroup
#define KC    32             // taps (x positions) per chunk = MFMA K
#define NC    321            // chunks: NC*KC = 10272 = D0 + TM
#define D0    10016          // t0 - p_start
#define RROWS 288            // A ring rows = TM + KC
#define ACOLS 40             // KC + 8 pad (row pitch 80B, bank-spread, 16B-aligned)
#define XCOLS 40

typedef short  bf16x8 __attribute__((ext_vector_type(8)));
typedef float  f32x4  __attribute__((ext_vector_type(4)));

__device__ __forceinline__ unsigned f2bf(float f) {
    unsigned u = __builtin_bit_cast(unsigned, f);
    return (u + 0x7FFFu + ((u >> 16) & 1u)) >> 16;   // RNE truncate to bf16 bits
}

__global__ __launch_bounds__(512, 4) void spatialize_mfma(
    const float* __restrict__ x, const float* __restrict__ ir,
    float* __restrict__ out)
{
    __shared__ ushort a_lds[2][RROWS][ACOLS];   // [ch][ring row][kk]  46080 B
    __shared__ ushort xb[2][BATCH][XCOLS];      // [buf][b][kk]        10240 B

    const int tid  = threadIdx.x;
    const int lane = tid & 63;
    const int wid  = tid >> 6;          // 8 waves
    const int wm   = wid >> 1;          // 0..3 : m-tiles [wm*4, wm*4+4)
    const int wn   = wid & 1;           // 0..1 : batches [wn*32, wn*32+32)
    const int t0   = OUT_T0 + blockIdx.x * TM;
    const int p_start = t0 - D0;

    // A-builder mapping (512 threads -> 2ch x 32 rows x 8 quads)
    const int bch = tid >> 8;           // channel
    const int bm  = (tid >> 3) & 31;    // row within new-row block
    const int bk0 = (tid & 7) * 4;      // kk quad start

    // x-stage mapping (512 threads -> 64 b x 8 float4)
    const int sb = tid >> 3;
    const int sg = tid & 7;

    // ---- prologue: build full initial A ring (virtual rows 0..TM-1 at phys KC..KC+TM-1) ----
#pragma unroll
    for (int s = 0; s < TM / KC; ++s) {
        const int m  = s * KC + bm;
        const int pr = KC + m;
        const int db = D0 + m - bk0;          // kk = bk0+q -> d = db - q
        unsigned h0 = (db-0 >= 0 && db-0 < K_TAPS) ? f2bf(ir[2*(db-0)+bch]) : 0u;
        unsigned h1 = (db-1 >= 0 && db-1 < K_TAPS) ? f2bf(ir[2*(db-1)+bch]) : 0u;
        unsigned h2 = (db-2 >= 0 && db-2 < K_TAPS) ? f2bf(ir[2*(db-2)+bch]) : 0u;
        unsigned h3 = (db-3 >= 0 && db-3 < K_TAPS) ? f2bf(ir[2*(db-3)+bch]) : 0u;
        uint2 w; w.x = h0 | (h1 << 16); w.y = h2 | (h3 << 16);
        *reinterpret_cast<uint2*>(&a_lds[bch][pr][bk0]) = w;
    }
    // stage xb[0] (chunk 0)
    {
        const float4 v = *reinterpret_cast<const float4*>(
            &x[(size_t)sb * T_LEN + p_start + sg * 4]);
        uint2 w; w.x = f2bf(v.x) | (f2bf(v.y) << 16);
                 w.y = f2bf(v.z) | (f2bf(v.w) << 16);
        *reinterpret_cast<uint2*>(&xb[0][sb][sg * 4]) = w;
    }
    __syncthreads();

    f32x4 acc[4][2][2];   // [mt][nt][ch]
#pragma unroll
    for (int mt = 0; mt < 4; ++mt)
#pragma unroll
        for (int nt = 0; nt < 2; ++nt)
#pragma unroll
            for (int ch = 0; ch < 2; ++ch)
                acc[mt][nt][ch] = (f32x4){0.f, 0.f, 0.f, 0.f};

    int vbase = KC;   // chunk 0 reads phys rows [KC, KC+TM)

    const int koff = 8 * (lane >> 4);   // k element offset of this lane's fragment
    const int lrow = lane & 15;

    for (int i = 0; i < NC; ++i) {
        const int  cur  = i & 1;
        const bool more = (i + 1 < NC);
        int vb2 = vbase - KC; if (vb2 < 0) vb2 += RROWS;

        // (1) issue next-chunk global loads early (hide latency under MFMA)
        float4 xv = make_float4(0.f, 0.f, 0.f, 0.f);
        float hv0 = 0.f, hv1 = 0.f, hv2 = 0.f, hv3 = 0.f;
        if (more) {
            const int p0n = p_start + (i + 1) * KC;
            xv = *reinterpret_cast<const float4*>(
                &x[(size_t)sb * T_LEN + p0n + sg * 4]);
            const int db = (D0 - (i + 1) * KC) + bm - bk0;
            hv0 = (db-0 >= 0 && db-0 < K_TAPS) ? ir[2*(db-0)+bch] : 0.f;
            hv1 = (db-1 >= 0 && db-1 < K_TAPS) ? ir[2*(db-1)+bch] : 0.f;
            hv2 = (db-2 >= 0 && db-2 < K_TAPS) ? ir[2*(db-2)+bch] : 0.f;
            hv3 = (db-3 >= 0 && db-3 < K_TAPS) ? ir[2*(db-3)+bch] : 0.f;
        }

        // (2) compute chunk i
        bf16x8 bfr0 = *reinterpret_cast<const bf16x8*>(&xb[cur][wn*32 +      lrow][koff]);
        bf16x8 bfr1 = *reinterpret_cast<const bf16x8*>(&xb[cur][wn*32 + 16 + lrow][koff]);
#pragma unroll
        for (int mt = 0; mt < 4; ++mt) {
            int g = vbase + wm * 64 + mt * 16; if (g >= RROWS) g -= RROWS;
            const int row = g + lrow;          // no mid-tile wrap: g%16==0, RROWS%16==0
#pragma unroll
            for (int ch = 0; ch < 2; ++ch) {
                bf16x8 af = *reinterpret_cast<const bf16x8*>(&a_lds[ch][row][koff]);
                acc[mt][0][ch] = __builtin_amdgcn_mfma_f32_16x16x32_bf16(
                    af, bfr0, acc[mt][0][ch], 0, 0, 0);
                acc[mt][1][ch] = __builtin_amdgcn_mfma_f32_16x16x32_bf16(
                    af, bfr1, acc[mt][1][ch], 0, 0, 0);
            }
        }

        // (3) write next-chunk LDS (regions disjoint from this chunk's reads)
        if (more) {
            uint2 wx; wx.x = f2bf(xv.x) | (f2bf(xv.y) << 16);
                      wx.y = f2bf(xv.z) | (f2bf(xv.w) << 16);
            *reinterpret_cast<uint2*>(&xb[cur ^ 1][sb][sg * 4]) = wx;
            uint2 wa; wa.x = f2bf(hv0) | (f2bf(hv1) << 16);
                      wa.y = f2bf(hv2) | (f2bf(hv3) << 16);
            *reinterpret_cast<uint2*>(&a_lds[bch][vb2 + bm][bk0]) = wa;
            vbase = vb2;
        }
        __syncthreads();
    }

    // ---- epilogue: D frag (col=lane&15 -> batch, row=(lane>>4)*4+reg -> time) ----
    const int r4 = (lane >> 4) * 4;
#pragma unroll
    for (int mt = 0; mt < 4; ++mt) {
        const int t4 = t0 + (wm * 4 + mt) * 16 + r4;
        if (t4 < OUT_T1) {
#pragma unroll
            for (int nt = 0; nt < 2; ++nt) {
                const int b = wn * 32 + nt * 16 + lrow;
#pragma unroll
                for (int ch = 0; ch < 2; ++ch) {
                    float4 v = make_float4(acc[mt][nt][ch][0], acc[mt][nt][ch][1],
                                           acc[mt][nt][ch][2], acc[mt][nt][ch][3]);
                    *reinterpret_cast<float4*>(
                        &out[(size_t)b * (2 * OUT_LEN) + (size_t)ch * OUT_LEN +
                             (t4 - OUT_T0)]) = v;
                }
            }
        }
    }
}

extern "C" void kernel_launch(void* const* d_in, const int* in_sizes, int n_in,
                              void* d_out, int out_size, void* d_ws, size_t ws_size,
                              hipStream_t stream)
{
    (void)in_sizes; (void)n_in; (void)d_ws; (void)ws_size; (void)out_size;
    const float* x  = (const float*)d_in[0];
    const float* ir = (const float*)d_in[1];
    float* out      = (float*)d_out;

    dim3 grid((OUT_LEN + TM - 1) / TM);   // 489 workgroups
    dim3 block(512);
    hipLaunchKernelGGL(spatialize_mfma, grid, block, 0, stream, x, ir, out);
}